// Round 8
// baseline (200.230 us; speedup 1.0000x reference)
//
#include <hip/hip_runtime.h>
#include <math.h>

// EdgeDetection: fused gray -> gauss3x3(sigma=0.8) -> scharr -> L2 mag, reflect-101
// R7: max-residency design. 128x8 tiles -> 8192 blocks (32 deep/CU). Gray-only
// LDS (6.5 KB), single barrier, vertical-first composite 5-taps (same verified
// math as R2-R6). __launch_bounds__(256,8) caps VGPR at 64 -> 32 waves/CU.
// XCD swizzle: id%8 = image, consecutive slots = vertically adjacent tiles.

#define IMG_H 1024
#define IMG_W 1024
#define TW 128
#define TH 8
#define GYR (TH + 4)     // 12 gray rows (y0-2 .. y0+9)
#define GXD 136          // gray cols/stride (x0-4 .. x0+131), 16B-aligned rows
#define NITEMS (GYR * (GXD / 4))   // 408 float4 staging items

// 1D gaussian sigma=0.8 k=3: e=exp(-0.78125); W0=1/(1+2e), W1=e/(1+2e)
#define W0f 0.52201125f
#define W1f 0.23899437f
// composite smooth a = conv([3,10,3],[W1,W0,W1]) (symmetric 5-tap):
#define AV0 0.71698311f   // 3*W1
#define AV1 3.95597745f   // 3*W0 + 10*W1
#define AV2 6.65407872f   // 10*W0 + 6*W1
// composite deriv d = conv([-1,0,1],[W1,W0,W1]) = [-W1,-W0,0,W0,W1]

__device__ __forceinline__ int reflect101(int v, int n) {
    v = (v < 0) ? -v : v;
    return (v >= n) ? (2 * n - 2 - v) : v;
}

__global__ __launch_bounds__(256, 8)
void edge_kernel(const float* __restrict__ in, float* __restrict__ out, int B) {
    __shared__ float sg[GYR][GXD];

    const int tid = threadIdx.x;
    const int id  = blockIdx.x;

    // XCD swizzle: with B==8, id%8 = image (one image per XCD under i%8 rr
    // mapping); slot walks y fastest -> vertically adjacent tiles temporally
    // adjacent on the same XCD (halo rows L2-hot). Correctness never depends
    // on the mapping.
    int img, slot;
    if (B == 8) { img = id & 7; slot = id >> 3; }
    else        { img = id >> 10; slot = id & 1023; }
    const int y_t = slot & 127;
    const int x_t = slot >> 7;

    const int x0 = x_t * TW;
    const int y0 = y_t * TH;

    const size_t plane = (size_t)IMG_H * IMG_W;
    const float* pr  = in + (size_t)img * 3 * plane;
    const float* pg  = pr + plane;
    const float* pbl = pg + plane;
    float* po = out + (size_t)img * 3 * plane;

    // ---- stage gray tile (float4 loads; scalar reflect only at x-edge tiles) ----
    for (int i = tid; i < NITEMS; i += 256) {
        int gy  = i / (GXD / 4);
        int gx4 = (i - gy * (GXD / 4)) * 4;
        int y = reflect101(y0 - 2 + gy, IMG_H);
        int x = x0 - 4 + gx4;
        float4 r4, g4, b4;
        if ((unsigned)x <= (unsigned)(IMG_W - 4)) {
            size_t o = ((size_t)y << 10) + x;
            r4 = *(const float4*)(pr  + o);
            g4 = *(const float4*)(pg  + o);
            b4 = *(const float4*)(pbl + o);
        } else {
            int x0e = reflect101(x,     IMG_W), x1e = reflect101(x + 1, IMG_W);
            int x2e = reflect101(x + 2, IMG_W), x3e = reflect101(x + 3, IMG_W);
            size_t ro = (size_t)y << 10;
            r4 = make_float4(pr[ro+x0e],  pr[ro+x1e],  pr[ro+x2e],  pr[ro+x3e]);
            g4 = make_float4(pg[ro+x0e],  pg[ro+x1e],  pg[ro+x2e],  pg[ro+x3e]);
            b4 = make_float4(pbl[ro+x0e], pbl[ro+x1e], pbl[ro+x2e], pbl[ro+x3e]);
        }
        float4 gr;
        gr.x = 0.299f * r4.x + 0.587f * g4.x + 0.114f * b4.x;
        gr.y = 0.299f * r4.y + 0.587f * g4.y + 0.114f * b4.y;
        gr.z = 0.299f * r4.z + 0.587f * g4.z + 0.114f * b4.z;
        gr.w = 0.299f * r4.w + 0.587f * g4.w + 0.114f * b4.w;
        *(float4*)&sg[gy][gx4] = gr;
    }
    __syncthreads();

    // ---- compute: thread = one output float4 (row ty, cols c4..c4+3) ----
    const int tx = tid & 31;
    const int ty = tid >> 5;          // 0..7
    const int c4 = tx * 4;            // 0..124

    // vertical-first: vs = v-smooth (A taps), vd = v-deriv (W taps), 8 cols
    // sg col j+c4+2 <-> abs col x0+c4-2+j, j=0..7
    float vs[8] = {}, vd[8] = {};
    #pragma unroll
    for (int r = 0; r < 5; ++r) {
        const float av = (r == 0 || r == 4) ? AV0 : ((r == 1 || r == 3) ? AV1 : AV2);
        const float dv = (r == 0) ? -W1f : (r == 1) ? -W0f : (r == 3) ? W0f : W1f;
        float4 va = *(const float4*)&sg[ty + r][c4];       // cols c4  ..c4+3 (use .z,.w)
        float4 vb = *(const float4*)&sg[ty + r][c4 + 4];   // cols c4+4..c4+7
        float4 vc = *(const float4*)&sg[ty + r][c4 + 8];   // cols c4+8..c4+11 (use .x,.y)
        const float g[8] = {va.z, va.w, vb.x, vb.y, vb.z, vb.w, vc.x, vc.y};
        #pragma unroll
        for (int j = 0; j < 8; ++j) {
            vs[j] += av * g[j];
            if (r != 2) vd[j] += dv * g[j];
        }
    }

    float4 m;
    float* mp = &m.x;
    #pragma unroll
    for (int k = 0; k < 4; ++k) {
        float sx = W1f * (vs[k+4] - vs[k]) + W0f * (vs[k+3] - vs[k+1]);
        float sy = AV0 * (vd[k] + vd[k+4]) + AV1 * (vd[k+1] + vd[k+3]) + AV2 * vd[k+2];
        mp[k] = sqrtf(sx * sx + sy * sy);
    }

    const size_t o = ((size_t)(y0 + ty) << 10) + (x0 + c4);
    *(float4*)(po + o)             = m;
    *(float4*)(po + o + plane)     = m;
    *(float4*)(po + o + 2 * plane) = m;
}

extern "C" void kernel_launch(void* const* d_in, const int* in_sizes, int n_in,
                              void* d_out, int out_size, void* d_ws, size_t ws_size,
                              hipStream_t stream) {
    const float* in = (const float*)d_in[0];
    float* out = (float*)d_out;
    const int B = in_sizes[0] / (3 * IMG_H * IMG_W);
    const int nblocks = B * (IMG_W / TW) * (IMG_H / TH);   // B * 1024
    edge_kernel<<<dim3(nblocks), dim3(256), 0, stream>>>(in, out, B);
}